// Round 1
// 294.718 us; speedup vs baseline: 1.0285x; 1.0285x over previous
//
#include <hip/hip_runtime.h>

#define N_ROWS   524288
#define W_BINS   101
#define EPS_F    1e-3f
#define RPB      64                    // rows per block (one 64x101 tile)
#define NBLK     (N_ROWS / RPB)        // 8192 blocks
#define TILE_F   (RPB * W_BINS)        // 6464 floats per tile (25,856 B LDS)
#define THREADS  128                   // 2 waves; each row split across a lane pair

typedef const float __attribute__((address_space(1)))* gptr_t;
typedef float __attribute__((address_space(3)))* sptr_t;

// One block = one 64-row tile, TWO waves. DMA the tile into LDS flat/coalesced
// (unchanged from the proven structure), but each row is now computed by a lane
// PAIR (l, l+32) inside one wave: wave0 -> rows 0..31, wave1 -> rows 32..63.
// Halves combine via one shfl_xor(32). This doubles waves/CU (6 -> 12) at the
// same LDS footprint and halves every serial exp/log chain. exp() results are
// kept in registers (e[50]) so pass 2 never touches LDS and never re-exps.
__global__ __launch_bounds__(THREADS) void mrl_main(const float* __restrict__ x,
                                                    const int* __restrict__ tgt,
                                                    float4* __restrict__ partial) {
    __shared__ float  sm[TILE_F];
    __shared__ float4 wsum[2];
    const int tid = threadIdx.x;                 // 0..127
    const int wv  = tid >> 6;                    // wave 0/1
    const float* gbase = x + (size_t)blockIdx.x * TILE_F;

    // Flat async DMA: 16 B/lane. Per call, wave w covers floats
    // [q*512 + w*256, +256) -- LDS dest base must be wave-uniform (+wv*256).
    // Source offset tid*4 == w*256 + lane*4 matches it exactly.
    #pragma unroll
    for (int q = 0; q < 12; ++q) {
        __builtin_amdgcn_global_load_lds((gptr_t)(gbase + q * 512 + tid * 4),
                                         (sptr_t)(sm + q * 512 + (wv << 8)), 16, 0, 0);
    }
    if (tid < 80) {                              // tail: floats 6144..6463
        __builtin_amdgcn_global_load_lds((gptr_t)(gbase + 6144 + tid * 4),
                                         (sptr_t)(sm + 6144 + (wv << 8)), 16, 0, 0);
    }

    const int r = (wv << 5) | (tid & 31);        // row 0..63
    const int h = (tid >> 5) & 1;                // which half of the row
    const int t = tgt[blockIdx.x * RPB + r];     // issued before the drain

    __syncthreads();                             // drains vmcnt -> tile visible

    // h==0 owns cols 0..50 (51), h==1 owns cols 51..100 (50). Max index read
    // is r*101+100 -> never crosses a row, no padding needed. Banks: pair-split
    // pattern lands 4 words/bank uniform per wave access = conflict-free.
    const float* rp = sm + r * W_BINS + h * 51;
    const int    cb = h * 51;                    // first col this lane owns

    // Pass 1: e_i = exp(x_i) kept in registers; accumulate se, sum(e*a), e_gt.
    float e[50];
    float e50 = 0.f;
    float se0 = 0.f, se1 = 0.f, sa0 = 0.f, sa1 = 0.f, eg = 0.f;
    #pragma unroll
    for (int i = 0; i < 50; i += 2) {
        float v0 = rp[i], v1 = rp[i + 1];
        float E0 = __expf(v0);
        float E1 = __expf(v1);
        e[i] = E0; e[i + 1] = E1;
        se0 += E0; sa0 += E0 * (float)(cb + i);
        se1 += E1; sa1 += E1 * (float)(cb + i + 1);
        eg = (cb + i     == t) ? E0 : eg;
        eg = (cb + i + 1 == t) ? E1 : eg;
    }
    if (h == 0) {                                // 51st element, col 50
        e50 = __expf(rp[50]);
        se0 += e50; sa0 += e50 * 50.0f;
        eg = (t == 50) ? e50 : eg;
    }
    float se  = se0 + se1;
    float sea = sa0 + sa1;

    // Combine the row pair (lanes l <-> l+32, same wave).
    se  += __shfl_xor(se, 32);
    sea += __shfl_xor(sea, 32);
    const float egt = eg + __shfl_xor(eg, 32);   // bit-exact e[t] (+0 from partner)
    const float inv = __builtin_amdgcn_rcpf(se);

    float sq = 0.f;
    if (h == 0) {                                // count mean-loss once per row
        float d = sea * inv - (float)t;
        sq = d * d;
    }

    // Pass 2: pure-register. Compare in e-space (scale-invariant): e_i < e_gt
    // <=> p_i < p_gt. i==t gives e==egt -> not lt -> counted in K.
    float rc0 = 0.f, rc1 = 0.f;
    int   k   = 0;
    #pragma unroll
    for (int i = 0; i < 50; i += 2) {
        float E0 = e[i], E1 = e[i + 1];
        bool  l0 = E0 < egt, l1 = E1 < egt;
        float q0 = (l0 ? E0 * inv : 0.f) + EPS_F;
        float q1 = (l1 ? E1 * inv : 0.f) + EPS_F;
        rc0 -= q0 * __logf(q0);
        rc1 -= q1 * __logf(q1);
        k   += (l0 ? 0 : 1) + (l1 ? 0 : 1);
    }
    if (h == 0) {
        bool  l = e50 < egt;
        float q = (l ? e50 * inv : 0.f) + EPS_F;
        rc0 -= q * __logf(q);
        k   += l ? 0 : 1;
    }
    float rc = rc0 + rc1;
    float kf = (float)k;                         // <= 101, exact in float

    // Wave butterfly over the 3 per-lane scalars (sq already half-zeroed).
    #pragma unroll
    for (int off = 32; off >= 1; off >>= 1) {
        sq += __shfl_xor(sq, off);
        rc += __shfl_xor(rc, off);
        kf += __shfl_xor(kf, off);
    }
    if ((tid & 63) == 0) wsum[wv] = make_float4(sq, rc, kf, 0.f);
    __syncthreads();
    if (tid == 0) {
        float4 a = wsum[0], b = wsum[1];
        partial[blockIdx.x] = make_float4(a.x + b.x, a.y + b.y, a.z + b.z, 0.f);
    }
}

__global__ __launch_bounds__(1024) void mrl_reduce(const float4* __restrict__ partial,
                                                   float* __restrict__ out) {
    double s = 0.0, r = 0.0, k = 0.0;
    #pragma unroll
    for (int i = 0; i < 8; ++i) {                // 8192 = 1024 * 8
        float4 v = partial[threadIdx.x + (i << 10)];
        s += (double)v.x; r += (double)v.y; k += (double)v.z;
    }
    #pragma unroll
    for (int off = 32; off >= 1; off >>= 1) {
        s += __shfl_xor(s, off);
        r += __shfl_xor(r, off);
        k += __shfl_xor(k, off);
    }
    __shared__ double sd[48];
    const int w = threadIdx.x >> 6;              // 16 waves
    if ((threadIdx.x & 63) == 0) { sd[w * 3 + 0] = s; sd[w * 3 + 1] = r; sd[w * 3 + 2] = k; }
    __syncthreads();
    if (threadIdx.x == 0) {
        double S = 0.0, R = 0.0, K = 0.0;
        #pragma unroll
        for (int i = 0; i < 16; ++i) { S += sd[i * 3]; R += sd[i * 3 + 1]; K += sd[i * 3 + 2]; }
        const double n = (double)N_ROWS;
        out[0] = (float)(0.1  * (S / n));        // LAMBDA_1 * mean_loss (0.2 * 0.5)
        out[1] = (float)(0.05 * (R / n));        // LAMBDA_2 * residue_loss
        out[2] = (float)(K / n);                 // batch_average_K
    }
}

extern "C" void kernel_launch(void* const* d_in, const int* in_sizes, int n_in,
                              void* d_out, int out_size, void* d_ws, size_t ws_size,
                              hipStream_t stream) {
    const float* x   = (const float*)d_in[0];
    const int*   tgt = (const int*)d_in[1];
    float*  out     = (float*)d_out;
    float4* partial = (float4*)d_ws;    // 8192 * 16 B = 128 KiB, well under ws_size

    mrl_main<<<NBLK, THREADS, 0, stream>>>(x, tgt, partial);
    mrl_reduce<<<1, 1024, 0, stream>>>(partial, out);
}

// Round 2
// 292.341 us; speedup vs baseline: 1.0369x; 1.0081x over previous
//
#include <hip/hip_runtime.h>

#define N_ROWS   524288
#define W_BINS   101
#define EPS_F    1e-3f
#define RPB      64                    // rows per block (one 64x101 tile)
#define NBLK     (N_ROWS / RPB)        // 8192 blocks
#define TILE_F   (RPB * W_BINS)        // 6464 floats per tile (25,856 B LDS)
#define THREADS  256                   // 4 waves; each row split across a lane QUARTET

typedef const float __attribute__((address_space(1)))* gptr_t;
typedef float __attribute__((address_space(3)))* sptr_t;

// One block = one 64-row tile, FOUR waves. Same flat DMA-to-LDS staging, but
// each row is computed by 4 lanes of one wave: row r = wv*16 + (tid&15),
// quarter h = (tid>>4)&3 owns cols {0..25, 26..50, 51..75, 76..100}.
// Quartet combine = shfl_xor(16) + shfl_xor(32). Same 25.9 KB LDS -> still
// 6 blocks/CU, now 24 waves/CU (was 12): doubles memory-request concurrency
// and halves every serial exp/log chain. exp() results stay in registers.
__global__ __launch_bounds__(THREADS) void mrl_main(const float* __restrict__ x,
                                                    const int* __restrict__ tgt,
                                                    float4* __restrict__ partial) {
    __shared__ float  sm[TILE_F];
    __shared__ float4 wsum[4];
    const int tid = threadIdx.x;                 // 0..255
    const int wv  = tid >> 6;                    // wave 0..3
    const float* gbase = x + (size_t)blockIdx.x * TILE_F;

    // Flat async DMA: 16 B/lane. Chunk q covers floats [q*1024, +1024);
    // wave w's sub-chunk [q*1024 + w*256, +256). LDS dest base is wave-uniform.
    #pragma unroll
    for (int q = 0; q < 6; ++q) {
        __builtin_amdgcn_global_load_lds((gptr_t)(gbase + q * 1024 + tid * 4),
                                         (sptr_t)(sm + q * 1024 + (wv << 8)), 16, 0, 0);
    }
    if (tid < 80) {                              // tail: floats 6144..6463
        __builtin_amdgcn_global_load_lds((gptr_t)(gbase + 6144 + tid * 4),
                                         (sptr_t)(sm + 6144 + (wv << 8)), 16, 0, 0);
    }

    const int r = (wv << 4) | (tid & 15);        // row 0..63 (16 rows per wave)
    const int h = (tid >> 4) & 3;                // which quarter of the row
    const int t = tgt[blockIdx.x * RPB + r];     // broadcast across the quartet

    __syncthreads();                             // drains vmcnt -> tile visible

    // h==0 owns 26 cols (0..25), h>0 own 25 each. Max index r*101+100 never
    // crosses a row. Banks: (5r + {0,26,19,12}) mod 32 spreads <=4-way.
    const int cb = (h == 0) ? 0 : (h * 25 + 1);  // {0,26,51,76}
    const float* rp = sm + r * W_BINS + cb;

    // Pass 1: e_i = exp(x_i) kept in registers; accumulate se, sum(e*a), e_gt.
    float e[25];
    float e25 = 0.f;
    float se0 = 0.f, se1 = 0.f, sa0 = 0.f, sa1 = 0.f, eg = 0.f;
    #pragma unroll
    for (int i = 0; i < 24; i += 2) {
        float E0 = __expf(rp[i]);
        float E1 = __expf(rp[i + 1]);
        e[i] = E0; e[i + 1] = E1;
        se0 += E0; sa0 += E0 * (float)(cb + i);
        se1 += E1; sa1 += E1 * (float)(cb + i + 1);
        eg = (cb + i     == t) ? E0 : eg;
        eg = (cb + i + 1 == t) ? E1 : eg;
    }
    {                                            // 25th owned col (i = 24)
        float E = __expf(rp[24]);
        e[24] = E;
        se0 += E; sa0 += E * (float)(cb + 24);
        eg = (cb + 24 == t) ? E : eg;
    }
    if (h == 0) {                                // 26th col of quarter 0 (col 25)
        e25 = __expf(rp[25]);
        se1 += e25; sa1 += e25 * 25.0f;
        eg = (t == 25) ? e25 : eg;
    }
    float se  = se0 + se1;
    float sea = sa0 + sa1;

    // Combine the 4 row-partners (tid bits 4,5 = h; same wave).
    se  += __shfl_xor(se, 16);  se  += __shfl_xor(se, 32);
    sea += __shfl_xor(sea, 16); sea += __shfl_xor(sea, 32);
    eg  += __shfl_xor(eg, 16);  eg  += __shfl_xor(eg, 32);
    const float egt = eg;                        // bit-exact e[t] (+0 from partners)
    const float inv = __builtin_amdgcn_rcpf(se);

    float sq = 0.f;
    if (h == 0) {                                // count mean-loss once per row
        float d = sea * inv - (float)t;
        sq = d * d;
    }

    // Pass 2: pure-register. e-space compare is scale-invariant; i==t -> not lt.
    float rc0 = 0.f, rc1 = 0.f;
    int   k   = 0;
    #pragma unroll
    for (int i = 0; i < 24; i += 2) {
        float E0 = e[i], E1 = e[i + 1];
        bool  l0 = E0 < egt, l1 = E1 < egt;
        float q0 = (l0 ? E0 * inv : 0.f) + EPS_F;
        float q1 = (l1 ? E1 * inv : 0.f) + EPS_F;
        rc0 -= q0 * __logf(q0);
        rc1 -= q1 * __logf(q1);
        k   += (l0 ? 0 : 1) + (l1 ? 0 : 1);
    }
    {
        float E = e[24];
        bool  l = E < egt;
        float q = (l ? E * inv : 0.f) + EPS_F;
        rc0 -= q * __logf(q);
        k   += l ? 0 : 1;
    }
    if (h == 0) {
        bool  l = e25 < egt;
        float q = (l ? e25 * inv : 0.f) + EPS_F;
        rc1 -= q * __logf(q);
        k   += l ? 0 : 1;
    }
    float rc = rc0 + rc1;
    float kf = (float)k;                         // <= 101, exact in float

    // Wave butterfly over the 3 per-lane scalars (sq nonzero only at h==0).
    #pragma unroll
    for (int off = 32; off >= 1; off >>= 1) {
        sq += __shfl_xor(sq, off);
        rc += __shfl_xor(rc, off);
        kf += __shfl_xor(kf, off);
    }
    if ((tid & 63) == 0) wsum[wv] = make_float4(sq, rc, kf, 0.f);
    __syncthreads();
    if (tid == 0) {
        float4 a = wsum[0], b = wsum[1], c = wsum[2], d = wsum[3];
        partial[blockIdx.x] = make_float4(a.x + b.x + c.x + d.x,
                                          a.y + b.y + c.y + d.y,
                                          a.z + b.z + c.z + d.z, 0.f);
    }
}

__global__ __launch_bounds__(1024) void mrl_reduce(const float4* __restrict__ partial,
                                                   float* __restrict__ out) {
    double s = 0.0, r = 0.0, k = 0.0;
    #pragma unroll
    for (int i = 0; i < 8; ++i) {                // 8192 = 1024 * 8
        float4 v = partial[threadIdx.x + (i << 10)];
        s += (double)v.x; r += (double)v.y; k += (double)v.z;
    }
    #pragma unroll
    for (int off = 32; off >= 1; off >>= 1) {
        s += __shfl_xor(s, off);
        r += __shfl_xor(r, off);
        k += __shfl_xor(k, off);
    }
    __shared__ double sd[48];
    const int w = threadIdx.x >> 6;              // 16 waves
    if ((threadIdx.x & 63) == 0) { sd[w * 3 + 0] = s; sd[w * 3 + 1] = r; sd[w * 3 + 2] = k; }
    __syncthreads();
    if (threadIdx.x == 0) {
        double S = 0.0, R = 0.0, K = 0.0;
        #pragma unroll
        for (int i = 0; i < 16; ++i) { S += sd[i * 3]; R += sd[i * 3 + 1]; K += sd[i * 3 + 2]; }
        const double n = (double)N_ROWS;
        out[0] = (float)(0.1  * (S / n));        // LAMBDA_1 * mean_loss (0.2 * 0.5)
        out[1] = (float)(0.05 * (R / n));        // LAMBDA_2 * residue_loss
        out[2] = (float)(K / n);                 // batch_average_K
    }
}

extern "C" void kernel_launch(void* const* d_in, const int* in_sizes, int n_in,
                              void* d_out, int out_size, void* d_ws, size_t ws_size,
                              hipStream_t stream) {
    const float* x   = (const float*)d_in[0];
    const int*   tgt = (const int*)d_in[1];
    float*  out     = (float*)d_out;
    float4* partial = (float4*)d_ws;    // 8192 * 16 B = 128 KiB, well under ws_size

    mrl_main<<<NBLK, THREADS, 0, stream>>>(x, tgt, partial);
    mrl_reduce<<<1, 1024, 0, stream>>>(partial, out);
}